// Round 1
// baseline (249.232 us; speedup 1.0000x reference)
//
#include <hip/hip_runtime.h>

// Problem constants
#define BB 4
#define NN 65536
#define CC 256
#define KK 4096
#define MIDC 128

// ---------------- Kernel S: scores -> sortable u32 keys ----------------
__global__ __launch_bounds__(256) void score_kernel(const float* __restrict__ cls,
                                                    unsigned* __restrict__ keys) {
    int i = blockIdx.x * 256 + threadIdx.x;          // 0 .. B*N-1
    float a = cls[i * 3 + 0];
    float b = cls[i * 3 + 1];
    float c = cls[i * 3 + 2];
    float s = fmaxf(fmaxf(a, b), c);
    unsigned u = __float_as_uint(s);
    u = (u & 0x80000000u) ? ~u : (u | 0x80000000u);  // order-preserving map
    keys[i] = u;
}

// ---------------- Kernel T: exact top-K per batch (radix select + bitonic sort) ----------------
// Composite key64 = (ukey << 32) | (u32)(~n)  -> all distinct; descending order of key64
// == descending score with ascending-index tie-break (jax.lax.top_k semantics).
__global__ __launch_bounds__(1024) void topk_kernel(const unsigned* __restrict__ keys,
                                                    int* __restrict__ idxout) {
    __shared__ unsigned long long sel[KK];
    __shared__ unsigned hist[256];
    __shared__ unsigned scan[256];
    __shared__ unsigned long long prefix_s;
    __shared__ int krem_s;
    __shared__ int cnt_s;
    __shared__ int done_s;

    int t = threadIdx.x;
    int b = blockIdx.x;
    const unsigned* kb = keys + (size_t)b * NN;

    if (t == 0) { prefix_s = 0ull; krem_s = KK; cnt_s = 0; done_s = 0; }
    __syncthreads();

    for (int r = 7; r >= 0; r--) {
        if (done_s) break;                    // uniform (shared) read after barrier
        int shift = r * 8;
        if (t < 256) hist[t] = 0u;
        __syncthreads();
        unsigned long long pfx = prefix_s;
        int krem = krem_s;
        for (int n = t; n < NN; n += 1024) {
            unsigned long long key = ((unsigned long long)kb[n] << 32) | (unsigned)(~n);
            bool match = (r == 7) || ((key >> (shift + 8)) == (pfx >> (shift + 8)));
            if (match) atomicAdd(&hist[(unsigned)(key >> shift) & 255u], 1u);
        }
        __syncthreads();
        // suffix-inclusive scan: scan[d] = sum hist[d..255]
        if (t < 256) scan[t] = hist[t];
        __syncthreads();
        for (int off = 1; off < 256; off <<= 1) {
            unsigned v = 0;
            if (t < 256) v = scan[t] + ((t + off) < 256 ? scan[t + off] : 0u);
            __syncthreads();
            if (t < 256) scan[t] = v;
            __syncthreads();
        }
        if (t < 256) {
            unsigned inc = scan[t];                         // >= bin t
            unsigned above = (t < 255) ? scan[t + 1] : 0u;  // > bin t
            if ((int)inc >= krem && (int)above < krem) {    // exactly one t satisfies
                prefix_s = pfx | ((unsigned long long)(unsigned)t << shift);
                int krem_new = krem - (int)above;
                krem_s = krem_new;
                if ((int)hist[t] == krem_new) done_s = 1;   // whole bin selected -> threshold final
            }
        }
        __syncthreads();
    }
    unsigned long long thresh = prefix_s;

    // collect exactly K elements with key >= thresh
    for (int n = t; n < NN; n += 1024) {
        unsigned long long key = ((unsigned long long)kb[n] << 32) | (unsigned)(~n);
        if (key >= thresh) {
            int pos = atomicAdd(&cnt_s, 1);
            if (pos < KK) sel[pos] = key;
        }
    }
    __syncthreads();

    // bitonic sort ascending over 4096 u64 (2048 pairs / stage, 1024 threads)
    for (unsigned size = 2; size <= KK; size <<= 1) {
        for (unsigned stride = size >> 1; stride > 0; stride >>= 1) {
            __syncthreads();
            for (unsigned p = t; p < KK / 2; p += 1024) {
                unsigned i = (p / stride) * (stride * 2) + (p % stride);
                unsigned j = i + stride;
                bool asc = ((i & size) == 0);
                unsigned long long a = sel[i], c = sel[j];
                if ((a > c) == asc) { sel[i] = c; sel[j] = a; }
            }
        }
    }
    __syncthreads();

    // emit descending: k-th largest = sel[K-1-k]; index = ~low32
    for (int k = t; k < KK; k += 1024) {
        unsigned long long key = sel[KK - 1 - k];
        unsigned n = ~((unsigned)key);
        idxout[b * KK + k] = (int)n;
    }
}

// ---------------- Kernel B: gather + GEMM1 (C->MID) + BN partial stats + origins ----------------
#define KT 32
__global__ __launch_bounds__(256) void gemm1_kernel(const float* __restrict__ feats,
                                                    const float* __restrict__ points,
                                                    const float* __restrict__ w1,
                                                    const int* __restrict__ idx,
                                                    float* __restrict__ h_out,
                                                    float* __restrict__ psum,
                                                    float* __restrict__ psq,
                                                    float* __restrict__ outOrig) {
    __shared__ __align__(16) float w1s[MIDC][68];  // stride 68: 16B-aligned rows, spread banks
    __shared__ __align__(16) float fs[KT][68];
    __shared__ int kidx[KT];
    __shared__ float redS[8][MIDC];
    __shared__ float redQ[8][MIDC];

    int t = threadIdx.x;
    int b = blockIdx.x >> 7;                 // K/KT = 128 tiles per batch
    int k0 = (blockIdx.x & 127) * KT;

    if (t < KT) kidx[t] = idx[b * KK + k0 + t];
    __syncthreads();

    if (t < KT * 3) {                        // gather origins (points)
        int k = t / 3, o = t % 3;
        outOrig[(size_t)(b * KK + k0 + k) * 3 + o] =
            points[((size_t)b * NN + kidx[k]) * 3 + o];
    }

    int tm = t & 31, tk = t >> 5;
    float acc[4][4] = {};

    for (int c0 = 0; c0 < CC; c0 += 64) {
        for (int e = t; e < MIDC * 64; e += 256) {      // stage w1 chunk
            int m = e >> 6, c = e & 63;
            w1s[m][c] = w1[m * CC + c0 + c];
        }
        for (int e = t; e < KT * 64; e += 256) {        // gather feats chunk (random columns)
            int k = e >> 6, c = e & 63;
            fs[k][c] = feats[((size_t)b * CC + c0 + c) * NN + kidx[k]];
        }
        __syncthreads();
#pragma unroll
        for (int c = 0; c < 64; c += 4) {
            float4 av[4], wv[4];
#pragma unroll
            for (int i = 0; i < 4; i++) av[i] = *reinterpret_cast<const float4*>(&fs[tk + 8 * i][c]);
#pragma unroll
            for (int j = 0; j < 4; j++) wv[j] = *reinterpret_cast<const float4*>(&w1s[tm + 32 * j][c]);
#pragma unroll
            for (int i = 0; i < 4; i++)
#pragma unroll
                for (int j = 0; j < 4; j++) {
                    acc[i][j] += av[i].x * wv[j].x;
                    acc[i][j] += av[i].y * wv[j].y;
                    acc[i][j] += av[i].z * wv[j].z;
                    acc[i][j] += av[i].w * wv[j].w;
                }
        }
        __syncthreads();
    }

    // write h + per-thread partial sums
    float ps[4] = {}, pq[4] = {};
#pragma unroll
    for (int i = 0; i < 4; i++) {
        int k = tk + 8 * i;
#pragma unroll
        for (int j = 0; j < 4; j++) {
            int m = tm + 32 * j;
            float v = acc[i][j];
            h_out[(size_t)(b * KK + k0 + k) * MIDC + m] = v;
            ps[j] += v;
            pq[j] += v * v;
        }
    }
#pragma unroll
    for (int j = 0; j < 4; j++) { redS[tk][tm + 32 * j] = ps[j]; redQ[tk][tm + 32 * j] = pq[j]; }
    __syncthreads();
    if (t < MIDC) {
        float s = 0.f, q = 0.f;
#pragma unroll
        for (int r = 0; r < 8; r++) { s += redS[r][t]; q += redQ[r][t]; }
        psum[blockIdx.x * MIDC + t] = s;
        psq[blockIdx.x * MIDC + t] = q;
    }
}

// ---------------- Kernel C: finalize BN stats -> scale/bias ----------------
__global__ __launch_bounds__(512) void bnstat_kernel(const float* __restrict__ psum,
                                                     const float* __restrict__ psq,
                                                     const float* __restrict__ gamma,
                                                     const float* __restrict__ beta,
                                                     float* __restrict__ sb) {
    __shared__ float rs[4][MIDC];
    __shared__ float rq[4][MIDC];
    int m = threadIdx.x & 127, g = threadIdx.x >> 7;
    float s = 0.f, q = 0.f;
    for (int blk = g; blk < 512; blk += 4) {
        s += psum[blk * MIDC + m];
        q += psq[blk * MIDC + m];
    }
    rs[g][m] = s; rq[g][m] = q;
    __syncthreads();
    if (threadIdx.x < MIDC) {
        float S = rs[0][m] + rs[1][m] + rs[2][m] + rs[3][m];
        float Q = rq[0][m] + rq[1][m] + rq[2][m] + rq[3][m];
        const float inv = 1.0f / (float)(BB * KK);
        float mean = S * inv;
        float var = Q * inv - mean * mean;
        float scale = gamma[m] * rsqrtf(var + 1e-5f);
        sb[m] = scale;
        sb[MIDC + m] = beta[m] - mean * scale;
    }
}

// ---------------- Kernel D: BN+ReLU+GEMM2(128->3)+clamp+add ----------------
__global__ __launch_bounds__(256) void out_kernel(const float* __restrict__ h,
                                                  const float* __restrict__ sb,
                                                  const float* __restrict__ w2,
                                                  const float* __restrict__ lim,
                                                  const float* __restrict__ orig,
                                                  float* __restrict__ preds,
                                                  float* __restrict__ offs) {
    int tid = blockIdx.x * 256 + threadIdx.x;
    int bk = tid >> 6;                // one wave per (b,k)
    int lane = tid & 63;
    const float* hp = h + (size_t)bk * MIDC;
    float h0 = hp[lane], h1 = hp[lane + 64];
    float y0 = fmaxf(h0 * sb[lane] + sb[MIDC + lane], 0.0f);
    float y1 = fmaxf(h1 * sb[lane + 64] + sb[MIDC + 64 + lane], 0.0f);
    float p0 = y0 * w2[lane]       + y1 * w2[lane + 64];
    float p1 = y0 * w2[128 + lane] + y1 * w2[192 + lane];
    float p2 = y0 * w2[256 + lane] + y1 * w2[320 + lane];
#pragma unroll
    for (int off = 32; off > 0; off >>= 1) {
        p0 += __shfl_xor(p0, off);
        p1 += __shfl_xor(p1, off);
        p2 += __shfl_xor(p2, off);
    }
    if (lane < 3) {
        float o = (lane == 0) ? p0 : ((lane == 1) ? p1 : p2);
        float L = lim[lane];
        float limited = fminf(fmaxf(o, -L), L);
        preds[bk * 3 + lane] = orig[bk * 3 + lane] + limited;
        offs[bk * 3 + lane] = o;
    }
}

// ---------------- launch ----------------
extern "C" void kernel_launch(void* const* d_in, const int* in_sizes, int n_in,
                              void* d_out, int out_size, void* d_ws, size_t ws_size,
                              hipStream_t stream) {
    const float* points   = (const float*)d_in[0];
    const float* features = (const float*)d_in[1];
    const float* cls      = (const float*)d_in[2];
    const float* w1       = (const float*)d_in[3];
    const float* gamma    = (const float*)d_in[4];
    const float* beta     = (const float*)d_in[5];
    const float* w2       = (const float*)d_in[6];
    const float* lim      = (const float*)d_in[7];

    float* out   = (float*)d_out;
    float* preds = out;                       // (B,K,3)
    float* orig  = out + BB * KK * 3;         // (B,K,3)
    float* offs  = out + 2 * BB * KK * 3;     // (B,K,3)

    float* wsf = (float*)d_ws;
    unsigned* keys = (unsigned*)wsf;                       // B*N
    int* idxw      = (int*)(wsf + BB * NN);                // B*K
    float* h       = wsf + BB * NN + BB * KK;              // B*K*MID
    float* psum    = h + (size_t)BB * KK * MIDC;           // 512*MID
    float* psq     = psum + 512 * MIDC;                    // 512*MID
    float* sb      = psq + 512 * MIDC;                     // 2*MID

    score_kernel<<<(BB * NN) / 256, 256, 0, stream>>>(cls, keys);
    topk_kernel<<<BB, 1024, 0, stream>>>(keys, idxw);
    gemm1_kernel<<<BB * (KK / KT), 256, 0, stream>>>(features, points, w1, idxw, h, psum, psq, orig);
    bnstat_kernel<<<1, 512, 0, stream>>>(psum, psq, gamma, beta, sb);
    out_kernel<<<(BB * KK * 64) / 256, 256, 0, stream>>>(h, sb, w2, lim, orig, preds, offs);
}